// Round 4
// baseline (2245.057 us; speedup 1.0000x reference)
//
#include <hip/hip_runtime.h>
#include <cstdio>

#define T_STEPS 336

// All scratch as device globals (no d_ws dependence). Every element is
// written each call before any read of it (no cross-call state).
__device__ float g_xg[336 * 2048];    // input-gate projection for batch 255
__device__ float g_h[337 * 512];      // h_0 .. h_336
__device__ float g_c[512];            // cell state
__device__ float g_blw[256 * 512];    // sampled BayesianLinear weight
__device__ float g_blb[256];          // sampled BayesianLinear bias
__device__ float g_whh[512 * 2048];   // sampled Whh

__device__ __forceinline__ float softplus_f(float x) {
  return (x > 20.f) ? x : log1pf(__expf(x));
}
__device__ __forceinline__ float sigmoid_f(float x) {
  return 1.f / (1.f + __expf(-x));
}

// Canary: fill d_out with 777. head_kernel later overwrites every element.
// If the bench reports absmax ~777, the head kernel's writes didn't land.
__global__ __launch_bounds__(256) void canary_kernel(float* out, int n) {
  int i = blockIdx.x * 256 + threadIdx.x;
  if (i < n) out[i] = 777.0f;
}

// ---------------- prep ----------------
// blocks    0..2687 : g_xg[t][g] = (x[255,t]*drop_x[255,t]) @ Wih + b  (sampled)
// blocks 2688..3199 : sample BLW -> g_blw
// block  3200       : sample BLb -> g_blb; zero g_h[0][:], g_c[:]
// blocks 3201..7296 : sample Whh -> g_whh
__global__ __launch_bounds__(256) void prep_kernel(
    const float* __restrict__ x, const float* __restrict__ drop_x,
    const float* __restrict__ wih_mu, const float* __restrict__ wih_rho, const float* __restrict__ eps_wih,
    const float* __restrict__ whh_mu, const float* __restrict__ whh_rho, const float* __restrict__ eps_whh,
    const float* __restrict__ b_mu, const float* __restrict__ b_rho, const float* __restrict__ eps_b,
    const float* __restrict__ blw_mu, const float* __restrict__ blw_rho, const float* __restrict__ eps_blw,
    const float* __restrict__ blb_mu, const float* __restrict__ blb_rho, const float* __restrict__ eps_blb)
{
  const int bid = blockIdx.x, tid = threadIdx.x;
  if (bid < 2688) {
    const int gid = bid * 256 + tid;
    const int t = gid >> 11;        // 0..335
    const int g = gid & 2047;       // gate column
    float acc = b_mu[g] + softplus_f(b_rho[g]) * eps_b[g];
    const int xoff = (255 * 336 + t) * 16;   // only batch element 255 survives the reshape quirk
    #pragma unroll
    for (int i = 0; i < 16; ++i) {
      float xv = x[xoff + i] * drop_x[xoff + i];
      int wi = i * 2048 + g;
      float w = wih_mu[wi] + softplus_f(wih_rho[wi]) * eps_wih[wi];
      acc = fmaf(xv, w, acc);
    }
    g_xg[gid] = acc;
  } else if (bid < 3200) {
    const int e = (bid - 2688) * 256 + tid;   // < 131072
    g_blw[e] = blw_mu[e] + softplus_f(blw_rho[e]) * eps_blw[e];
  } else if (bid == 3200) {
    g_blb[tid] = blb_mu[tid] + softplus_f(blb_rho[tid]) * eps_blb[tid];
    if (tid < 256) { g_h[tid] = 0.f; g_h[256 + tid] = 0.f; g_c[tid] = 0.f; g_c[256 + tid] = 0.f; }
  } else {
    const int e = (bid - 3201) * 256 + tid;   // < 1048576
    g_whh[e] = whh_mu[e] + softplus_f(whh_rho[e]) * eps_whh[e];
  }
}

// ---------------- one LSTM timestep ----------------
// 336 stream-ordered launches => coherent g_h/g_c between steps, no custom sync.
// 32 blocks x 256 threads. Block b owns h-indices [16b,16b+16).
// Thread: cl=tid&63 selects (gate,k), q=tid>>6 selects row-quarter (128 rows).
__global__ __launch_bounds__(256) void step_kernel(int t) {
  const int b = blockIdx.x, tid = threadIdx.x;
  const int cl = tid & 63;
  const int q = tid >> 6;                 // 0..3
  const int gate = cl >> 4, kl = cl & 15;
  const int col = gate * 512 + b * 16 + kl;

  __shared__ float hs[512];
  __shared__ float part[4][64];

  for (int i = tid; i < 512; i += 256) hs[i] = g_h[t * 512 + i];
  __syncthreads();

  float acc = 0.f;
  const float* wcol = g_whh + col + q * 128 * 2048;
  #pragma unroll 8
  for (int r = 0; r < 128; ++r) acc = fmaf(hs[q * 128 + r], wcol[r * 2048], acc);
  part[q][cl] = acc;
  __syncthreads();

  if (tid < 64) {
    float g = g_xg[t * 2048 + (tid >> 4) * 512 + b * 16 + (tid & 15)]
            + part[0][tid] + part[1][tid] + part[2][tid] + part[3][tid];
    part[0][tid] = g;   // reuse as gate buffer
  }
  __syncthreads();

  if (tid < 16) {
    const int k = b * 16 + tid;
    float ig = sigmoid_f(part[0][tid]);
    float fg = sigmoid_f(part[0][16 + tid]);
    float gg = tanhf(part[0][32 + tid]);
    float og = sigmoid_f(part[0][48 + tid]);
    float c = fg * g_c[k] + ig * gg;
    g_c[k] = c;
    g_h[(t + 1) * 512 + k] = og * tanhf(c);
  }
}

// ---------------- head ----------------
// block j: last[j] = g_h[81+j]  (reshape(T,B,H)[-1] => h_{t=80+j} of batch 255)
// y[l] = relu(sum_k last*drop_h[j] . BLW[l] + BLb[l]) * drop_l[j,l]
// out[j,o] = sum_l y[l]*lin_w[o,l]
__global__ __launch_bounds__(256) void head_kernel(
    const float* __restrict__ drop_h, const float* __restrict__ drop_l,
    const float* __restrict__ lin_w, float* __restrict__ out)
{
  const int j = blockIdx.x, tid = threadIdx.x;
  __shared__ float hd[512];
  __shared__ float y[256];

  for (int k = tid; k < 512; k += 256)
    hd[k] = g_h[(81 + j) * 512 + k] * drop_h[j * 512 + k];
  __syncthreads();

  {
    const int l = tid;
    float acc = g_blb[l];
    const float* wrow = g_blw + l * 512;
    #pragma unroll 8
    for (int k = 0; k < 512; ++k) acc = fmaf(hd[k], wrow[k], acc);
    acc = fmaxf(acc, 0.f);
    y[l] = acc * drop_l[j * 256 + l];
  }
  __syncthreads();

  if (tid < 10) {
    float acc = 0.f;
    const float* lrow = lin_w + tid * 256;
    #pragma unroll 8
    for (int l = 0; l < 256; ++l) acc = fmaf(y[l], lrow[l], acc);
    out[j * 10 + tid] = acc;
  }
}

// ---------------- launch ----------------
extern "C" void kernel_launch(void* const* d_in, const int* in_sizes, int n_in,
                              void* d_out, int out_size, void* d_ws, size_t ws_size,
                              hipStream_t stream) {
  fprintf(stderr, "[diag] kernel_launch (fp32 I/O): n_in=%d out_size=%d ws_size=%zu\n",
          n_in, out_size, ws_size);

  const float* x        = (const float*)d_in[0];
  const float* drop_x   = (const float*)d_in[1];
  const float* drop_h   = (const float*)d_in[2];
  const float* drop_l   = (const float*)d_in[3];
  const float* wih_mu   = (const float*)d_in[4];
  const float* wih_rho  = (const float*)d_in[5];
  const float* eps_wih  = (const float*)d_in[6];
  const float* whh_mu   = (const float*)d_in[7];
  const float* whh_rho  = (const float*)d_in[8];
  const float* eps_whh  = (const float*)d_in[9];
  const float* b_mu     = (const float*)d_in[10];
  const float* b_rho    = (const float*)d_in[11];
  const float* eps_b    = (const float*)d_in[12];
  const float* blw_mu   = (const float*)d_in[13];
  const float* blw_rho  = (const float*)d_in[14];
  const float* eps_blw  = (const float*)d_in[15];
  const float* blb_mu   = (const float*)d_in[16];
  const float* blb_rho  = (const float*)d_in[17];
  const float* eps_blb  = (const float*)d_in[18];
  const float* lin_w    = (const float*)d_in[19];

  // 1) canary: if head_kernel's writes never land, absmax ~777 tells us.
  canary_kernel<<<(out_size + 255) / 256, 256, 0, stream>>>((float*)d_out, out_size);

  // 2) sample weights, project inputs, zero state.
  prep_kernel<<<7297, 256, 0, stream>>>(
      x, drop_x, wih_mu, wih_rho, eps_wih, whh_mu, whh_rho, eps_whh,
      b_mu, b_rho, eps_b, blw_mu, blw_rho, eps_blw, blb_mu, blb_rho, eps_blb);

  // 3) serial recurrence, stream-ordered.
  for (int t = 0; t < T_STEPS; ++t) {
    step_kernel<<<32, 256, 0, stream>>>(t);
  }

  // 4) head -> overwrites every d_out element.
  head_kernel<<<256, 256, 0, stream>>>(drop_h, drop_l, lin_w, (float*)d_out);

  hipError_t e = hipGetLastError();
  fprintf(stderr, "[diag] post-launch hipGetLastError=%d (%s)\n",
          (int)e, hipGetErrorString(e));
}